// Round 1
// 847.794 us; speedup vs baseline: 1.2234x; 1.2234x over previous
//
#include <hip/hip_runtime.h>

#define R_ 64
#define C_ 2048
#define E_ 512
#define H_ 8
#define D_ 64

constexpr int CE = C_ * E_;                 // 1,048,576
constexpr long long OUT_ELEMS = 67108864LL; // R*C*E floats
// d_out layout: [0, OUT_ELEMS) = out ; [OUT_ELEMS, +33554432 floats) = attn
// scratch aliasing: xT(bf16, 67.1M shorts) lives in out region (dead before
// out_mfma); Tbf (16.8M shorts) lives in attn region (dead before attn_mfma).

typedef __attribute__((ext_vector_type(8))) short bf16x8;
typedef __attribute__((ext_vector_type(4))) float f32x4;

__device__ __forceinline__ unsigned short f2bf(float f) {
    union { float f; unsigned u; } v; v.f = f;
    unsigned r = v.u + 0x7FFFu + ((v.u >> 16) & 1u);  // RNE
    return (unsigned short)(r >> 16);
}

typedef __attribute__((address_space(1))) unsigned char glob_t;
typedef __attribute__((address_space(3))) unsigned char lds_t;
__device__ __forceinline__ void gld_lds16(const unsigned short* g, unsigned short* l) {
    __builtin_amdgcn_global_load_lds((const glob_t*)g, (lds_t*)l, 16, 0, 0);
}

// ---------------- prep: xbar = mean_r x ; xT[b][e][c] = bf16(x[b][c][e]) ----
__global__ __launch_bounds__(256) void prep(const float* __restrict__ x,
                                            float* __restrict__ xbar,
                                            unsigned short* __restrict__ xT) {
    __shared__ float Ts[64][65];
    int c0 = blockIdx.x * 64, e0 = blockIdx.y * 64;
    int t = threadIdx.x;
    int r = t >> 2;            // 0..63 (c-local)
    int cs = (t & 3) * 16;     // e-local base, 16 floats
    float acc[16] = {};
    for (int b = 0; b < 64; ++b) {
        const float* xp = x + ((size_t)b * C_ + c0 + r) * E_ + e0 + cs;
        float vv[16];
        float4 v0 = *(const float4*)(xp);
        float4 v1 = *(const float4*)(xp + 4);
        float4 v2 = *(const float4*)(xp + 8);
        float4 v3 = *(const float4*)(xp + 12);
        vv[0]=v0.x; vv[1]=v0.y; vv[2]=v0.z; vv[3]=v0.w;
        vv[4]=v1.x; vv[5]=v1.y; vv[6]=v1.z; vv[7]=v1.w;
        vv[8]=v2.x; vv[9]=v2.y; vv[10]=v2.z; vv[11]=v2.w;
        vv[12]=v3.x; vv[13]=v3.y; vv[14]=v3.z; vv[15]=v3.w;
        #pragma unroll
        for (int i = 0; i < 16; ++i) acc[i] += vv[i];
        __syncthreads();   // protect prior iteration's Ts reads
        #pragma unroll
        for (int i = 0; i < 16; ++i) Ts[cs + i][r] = vv[i];  // transpose into LDS
        __syncthreads();
        // read back rows of transposed tile: e-row j, c cols cs..cs+15
        unsigned short ob[16];
        #pragma unroll
        for (int i = 0; i < 16; ++i) ob[i] = f2bf(Ts[r][cs + i]);
        unsigned short* op = xT + ((size_t)b * E_ + e0 + r) * C_ + c0 + cs;
        *(bf16x8*)(op)     = *(bf16x8*)(ob);
        *(bf16x8*)(op + 8) = *(bf16x8*)(ob + 8);
    }
    float* xb = xbar + (size_t)(c0 + r) * E_ + e0 + cs;
    #pragma unroll
    for (int i = 0; i < 16; ++i) xb[i] = acc[i] * 0.015625f;
}

// -------- fp32 NT GEMM 64x64 tiles: C[m][n] = sum_k A[m][k]*B[n][k] + bias --
__global__ __launch_bounds__(256) void gemm_nt(const float* __restrict__ A, int lda,
                                               const float* __restrict__ B, int ldb,
                                               float* __restrict__ Cmat, int ldc, int K,
                                               const float* __restrict__ bias, int biasPerM) {
    __shared__ float As[64][65];
    __shared__ float Bs[64][65];   // stored transposed: Bs[k][n]
    int m0 = blockIdx.y * 64, n0 = blockIdx.x * 64;
    int t = threadIdx.x, tx = t & 15, ty = t >> 4;
    float acc[4][4] = {};
    for (int k0 = 0; k0 < K; k0 += 64) {
        #pragma unroll
        for (int i = 0; i < 4; ++i) {
            int rr = ty + i * 16, cc = tx * 4;
            float4 av = *(const float4*)(A + (size_t)(m0 + rr) * lda + k0 + cc);
            As[rr][cc] = av.x; As[rr][cc + 1] = av.y; As[rr][cc + 2] = av.z; As[rr][cc + 3] = av.w;
            float4 bv = *(const float4*)(B + (size_t)(n0 + rr) * ldb + k0 + cc);
            Bs[cc][rr] = bv.x; Bs[cc + 1][rr] = bv.y; Bs[cc + 2][rr] = bv.z; Bs[cc + 3][rr] = bv.w;
        }
        __syncthreads();
        for (int kk = 0; kk < 64; ++kk) {
            float a[4];
            #pragma unroll
            for (int i = 0; i < 4; ++i) a[i] = As[ty + 16 * i][kk];
            float4 b4 = *(const float4*)(&Bs[kk][tx * 4]);
            #pragma unroll
            for (int i = 0; i < 4; ++i) {
                acc[i][0] += a[i] * b4.x; acc[i][1] += a[i] * b4.y;
                acc[i][2] += a[i] * b4.z; acc[i][3] += a[i] * b4.w;
            }
        }
        __syncthreads();
    }
    #pragma unroll
    for (int i = 0; i < 4; ++i) {
        int m = m0 + ty + 16 * i, n = n0 + tx * 4;
        float4 o;
        if (biasPerM) {
            float bm = bias[m];
            o.x = acc[i][0] + bm; o.y = acc[i][1] + bm; o.z = acc[i][2] + bm; o.w = acc[i][3] + bm;
        } else {
            o.x = acc[i][0] + bias[n]; o.y = acc[i][1] + bias[n + 1];
            o.z = acc[i][2] + bias[n + 2]; o.w = acc[i][3] + bias[n + 3];
        }
        *(float4*)(Cmat + (size_t)m * ldc + n) = o;
    }
}

// --------------------------- softmax q (over D), emit bf16 (fp32 not needed)
__global__ __launch_bounds__(256) void softmax_q(const float* __restrict__ q,
                                                 unsigned short* __restrict__ qbf) {
    int t = threadIdx.x;
    int chunk = blockIdx.x * 4 + (t >> 6);
    int lane = t & 63;
    const float* p = q + (size_t)chunk * 64;
    float v = p[lane];
    float m = v;
    for (int o = 32; o; o >>= 1) m = fmaxf(m, __shfl_xor(m, o));
    float e = expf(v - m);
    float s = e;
    for (int o = 32; o; o >>= 1) s += __shfl_xor(s, o);
    qbf[(size_t)chunk * 64 + lane] = f2bf(e / s * 0.125f);
}

// ---------- softmax k (over C), emit bf16 row-major [j][c] + transposed [c][j]
__global__ __launch_bounds__(256) void softmax_k(const float* __restrict__ kT,
                                                 unsigned short* __restrict__ kbf,
                                                 unsigned short* __restrict__ kbfT) {
    __shared__ float red[256];
    int j = blockIdx.x, t = threadIdx.x;
    const float* row = kT + (size_t)j * C_;
    float vals[8];
    float mx = -1e30f;
    #pragma unroll
    for (int i = 0; i < 8; ++i) { vals[i] = row[t + 256 * i]; mx = fmaxf(mx, vals[i]); }
    red[t] = mx; __syncthreads();
    for (int s = 128; s; s >>= 1) { if (t < s) red[t] = fmaxf(red[t], red[t + s]); __syncthreads(); }
    mx = red[0]; __syncthreads();
    float sum = 0.f;
    #pragma unroll
    for (int i = 0; i < 8; ++i) { vals[i] = expf(vals[i] - mx); sum += vals[i]; }
    red[t] = sum; __syncthreads();
    for (int s = 128; s; s >>= 1) { if (t < s) red[t] += red[t + s]; __syncthreads(); }
    float inv = 1.0f / red[0];
    #pragma unroll
    for (int i = 0; i < 8; ++i) {
        unsigned short bv = f2bf(vals[i] * inv);
        kbf[(size_t)j * C_ + t + 256 * i] = bv;
        kbfT[(size_t)(t + 256 * i) * 512 + j] = bv;   // scattered, 2 MB total
    }
}

// --------------------------------- tiny fp32 -> bf16 converter (for Wv)
__global__ __launch_bounds__(256) void tobf16(const float* __restrict__ src,
                                              unsigned short* __restrict__ dst) {
    int i = blockIdx.x * 256 + threadIdx.x;  // one thread = 8 elems
    const float* p = src + (size_t)i * 8;
    unsigned short o[8];
    #pragma unroll
    for (int j = 0; j < 8; ++j) o[j] = f2bf(p[j]);
    *(bf16x8*)(dst + (size_t)i * 8) = *(bf16x8*)o;
}

// ---- T[b][j][e] = sum_c ksm[j][c] * x[b][c][e] : bf16 MFMA NT, 128x128 tile
// A = kbf[j=512][c=2048] bf16 row-major; B = xT[b][e=512][c=2048] bf16.
// Output now written in bf16 (only consumer is ctx_mfma).
__global__ __launch_bounds__(256) void t_gemm(const unsigned short* __restrict__ Abf,
                                              const unsigned short* __restrict__ xT,
                                              unsigned short* __restrict__ Tout) {
    __shared__ __align__(16) unsigned short As[128 * 32];  // no padding (gld_lds)
    __shared__ __align__(16) unsigned short Bs[128 * 32];
    const int b = blockIdx.z;
    const unsigned short* Bg = xT + (size_t)b * CE;  // 512*2048 shorts
    const int m0 = blockIdx.y * 128, n0 = blockIdx.x * 128;
    const int t = threadIdx.x, lane = t & 63, w = t >> 6;
    const int wm = (w >> 1) * 64, wn = (w & 1) * 64;
    const int l15 = lane & 15, quad = lane >> 4;
    const int srow = t >> 2, sseg = (t & 3) * 8;  // stage: row, 8-short segment

    f32x4 acc[4][4];
    #pragma unroll
    for (int i = 0; i < 4; ++i)
        #pragma unroll
        for (int j = 0; j < 4; ++j) acc[i][j] = (f32x4){0.f, 0.f, 0.f, 0.f};

    for (int k0 = 0; k0 < C_; k0 += 32) {
        gld_lds16(Abf + (size_t)(m0 + srow) * C_ + k0 + sseg,        &As[srow * 32 + sseg]);
        gld_lds16(Abf + (size_t)(m0 + 64 + srow) * C_ + k0 + sseg,   &As[(64 + srow) * 32 + sseg]);
        gld_lds16(Bg  + (size_t)(n0 + srow) * C_ + k0 + sseg,        &Bs[srow * 32 + sseg]);
        gld_lds16(Bg  + (size_t)(n0 + 64 + srow) * C_ + k0 + sseg,   &Bs[(64 + srow) * 32 + sseg]);
        __syncthreads();
        bf16x8 af[4], bfr[4];
        #pragma unroll
        for (int mi = 0; mi < 4; ++mi)
            af[mi] = *(const bf16x8*)(&As[(wm + mi * 16 + l15) * 32 + quad * 8]);
        #pragma unroll
        for (int ni = 0; ni < 4; ++ni)
            bfr[ni] = *(const bf16x8*)(&Bs[(wn + ni * 16 + l15) * 32 + quad * 8]);
        #pragma unroll
        for (int mi = 0; mi < 4; ++mi)
            #pragma unroll
            for (int ni = 0; ni < 4; ++ni)
                acc[mi][ni] = __builtin_amdgcn_mfma_f32_16x16x32_bf16(
                    af[mi], bfr[ni], acc[mi][ni], 0, 0, 0);
        __syncthreads();
    }
    unsigned short* To = Tout + (size_t)b * 262144;
    #pragma unroll
    for (int mi = 0; mi < 4; ++mi)
        #pragma unroll
        for (int ni = 0; ni < 4; ++ni)
            #pragma unroll
            for (int r = 0; r < 4; ++r) {
                int m = m0 + wm + mi * 16 + quad * 4 + r;
                int n = n0 + wn + ni * 16 + l15;
                To[(size_t)m * 512 + n] = f2bf(acc[mi][ni][r]);
            }
}

// ------ ctxT[b,h][e][d] = sum_k Wv[h*64+e][k] * T[b][h*64+d][k]  (no bias;
//        the bv term is folded into out_mfma as 0.125*bv since sum_d q = 0.125)
// One wave per (b,h); K=512; direct-from-global MFMA fragments, no LDS.
__global__ __launch_bounds__(256) void ctx_mfma(const unsigned short* __restrict__ Tbf,
                                                const unsigned short* __restrict__ Wvbf,
                                                unsigned short* __restrict__ ctxT) {
    const int t = threadIdx.x, lane = t & 63, w = t >> 6;
    const int z = blockIdx.x * 4 + w, b = z >> 3, h = z & 7;
    const int l15 = lane & 15, quad = lane >> 4;
    f32x4 acc[4][4];
    #pragma unroll
    for (int i = 0; i < 4; ++i)
        #pragma unroll
        for (int j = 0; j < 4; ++j) acc[i][j] = (f32x4){0.f, 0.f, 0.f, 0.f};
    for (int ks = 0; ks < 16; ++ks) {
        bf16x8 af[4], bfr[4];
        #pragma unroll
        for (int mi = 0; mi < 4; ++mi)
            af[mi] = *(const bf16x8*)(Wvbf + (size_t)(h * 64 + mi * 16 + l15) * 512 + ks * 32 + quad * 8);
        #pragma unroll
        for (int ni = 0; ni < 4; ++ni)
            bfr[ni] = *(const bf16x8*)(Tbf + ((size_t)b * 512 + h * 64 + ni * 16 + l15) * 512 + ks * 32 + quad * 8);
        #pragma unroll
        for (int mi = 0; mi < 4; ++mi)
            #pragma unroll
            for (int ni = 0; ni < 4; ++ni)
                acc[mi][ni] = __builtin_amdgcn_mfma_f32_16x16x32_bf16(
                    af[mi], bfr[ni], acc[mi][ni], 0, 0, 0);
    }
    #pragma unroll
    for (int mi = 0; mi < 4; ++mi)
        #pragma unroll
        for (int ni = 0; ni < 4; ++ni)
            #pragma unroll
            for (int r = 0; r < 4; ++r) {
                int e = mi * 16 + quad * 4 + r, d = ni * 16 + l15;
                ctxT[(size_t)z * 4096 + e * 64 + d] = f2bf(acc[mi][ni][r]);
            }
}

// ---- out[b][n][h*64+e] = sum_d qbf[n][h*64+d] * ctxT[b,h][e][d] + 0.125*bv
// Block: 128 n-rows x full E; 4 waves = (2 n-halves) x (2 head-groups of 4).
__global__ __launch_bounds__(256) void out_mfma(const unsigned short* __restrict__ qbf,
                                                const unsigned short* __restrict__ ctxT,
                                                const float* __restrict__ bv,
                                                float* __restrict__ outp) {
    const int b = blockIdx.y;
    const int n0 = blockIdx.x * 128;
    const int t = threadIdx.x, lane = t & 63, w = t >> 6;
    const int wm = (w & 1) * 64;
    const int h0 = (w >> 1) * 4;
    const int l15 = lane & 15, quad = lane >> 4;
    for (int hi = 0; hi < 4; ++hi) {
        const int h = h0 + hi;
        f32x4 acc[4][4];
        #pragma unroll
        for (int i = 0; i < 4; ++i)
            #pragma unroll
            for (int j = 0; j < 4; ++j) acc[i][j] = (f32x4){0.f, 0.f, 0.f, 0.f};
        #pragma unroll
        for (int ks = 0; ks < 2; ++ks) {
            bf16x8 af[4], bfr[4];
            #pragma unroll
            for (int mi = 0; mi < 4; ++mi)
                af[mi] = *(const bf16x8*)(qbf + (size_t)(n0 + wm + mi * 16 + l15) * 512 + h * 64 + ks * 32 + quad * 8);
            #pragma unroll
            for (int ni = 0; ni < 4; ++ni)
                bfr[ni] = *(const bf16x8*)(ctxT + (size_t)(b * 8 + h) * 4096 + (ni * 16 + l15) * 64 + ks * 32 + quad * 8);
            #pragma unroll
            for (int mi = 0; mi < 4; ++mi)
                #pragma unroll
                for (int ni = 0; ni < 4; ++ni)
                    acc[mi][ni] = __builtin_amdgcn_mfma_f32_16x16x32_bf16(
                        af[mi], bfr[ni], acc[mi][ni], 0, 0, 0);
        }
        #pragma unroll
        for (int ni = 0; ni < 4; ++ni) {
            float bvv = 0.125f * bv[h * 64 + ni * 16 + l15];
            #pragma unroll
            for (int mi = 0; mi < 4; ++mi)
                #pragma unroll
                for (int r = 0; r < 4; ++r) {
                    int n = n0 + wm + mi * 16 + quad * 4 + r;
                    outp[((size_t)b * C_ + n) * E_ + h * 64 + ni * 16 + l15] = acc[mi][ni][r] + bvv;
                }
        }
    }
}

// ---- attn[h][n][m] = sum_d qbf[n][h*64+d] * kbfT[m][h*64+d]  (K=64, MFMA)
// Block: 128x128 tile, 4 waves (2x2), direct-from-global fragments.
__global__ __launch_bounds__(256) void attn_mfma(const unsigned short* __restrict__ qbf,
                                                 const unsigned short* __restrict__ kbfT,
                                                 float* __restrict__ attn) {
    const int h = blockIdx.z;
    const int m0 = blockIdx.x * 128, n0 = blockIdx.y * 128;
    const int t = threadIdx.x, lane = t & 63, w = t >> 6;
    const int wm = (w >> 1) * 64, wn = (w & 1) * 64;
    const int l15 = lane & 15, quad = lane >> 4;
    f32x4 acc[4][4];
    #pragma unroll
    for (int i = 0; i < 4; ++i)
        #pragma unroll
        for (int j = 0; j < 4; ++j) acc[i][j] = (f32x4){0.f, 0.f, 0.f, 0.f};
    #pragma unroll
    for (int ks = 0; ks < 2; ++ks) {
        bf16x8 af[4], bfr[4];
        #pragma unroll
        for (int mi = 0; mi < 4; ++mi)
            af[mi] = *(const bf16x8*)(qbf + (size_t)(n0 + wm + mi * 16 + l15) * 512 + h * 64 + ks * 32 + quad * 8);
        #pragma unroll
        for (int ni = 0; ni < 4; ++ni)
            bfr[ni] = *(const bf16x8*)(kbfT + (size_t)(m0 + wn + ni * 16 + l15) * 512 + h * 64 + ks * 32 + quad * 8);
        #pragma unroll
        for (int mi = 0; mi < 4; ++mi)
            #pragma unroll
            for (int ni = 0; ni < 4; ++ni)
                acc[mi][ni] = __builtin_amdgcn_mfma_f32_16x16x32_bf16(
                    af[mi], bfr[ni], acc[mi][ni], 0, 0, 0);
    }
    #pragma unroll
    for (int mi = 0; mi < 4; ++mi)
        #pragma unroll
        for (int ni = 0; ni < 4; ++ni)
            #pragma unroll
            for (int r = 0; r < 4; ++r) {
                int n = n0 + wm + mi * 16 + quad * 4 + r;
                int m = m0 + wn + ni * 16 + l15;
                attn[(size_t)h * C_ * C_ + (size_t)n * C_ + m] = acc[mi][ni][r];
            }
}

extern "C" void kernel_launch(void* const* d_in, const int* in_sizes, int n_in,
                              void* d_out, int out_size, void* d_ws, size_t ws_size,
                              hipStream_t stream) {
    const float* x  = (const float*)d_in[0];
    const float* Wq = (const float*)d_in[1];
    const float* bq = (const float*)d_in[2];
    const float* Wk = (const float*)d_in[3];
    const float* bk = (const float*)d_in[4];
    const float* Wv = (const float*)d_in[5];
    const float* bv = (const float*)d_in[6];
    float* out = (float*)d_out;

    float* ws = (float*)d_ws;
    float* xbar = ws;                                        // 1,048,576 fl
    float* qsm  = ws + 1048576;                              // 1,048,576 fl (logits; softmax reads only)
    float* kT   = ws + 2097152;                              // 1,048,576 fl [j][c] logits
    unsigned short* kbf  = (unsigned short*)(ws + 3145728);  // 1,048,576 us [j][c]
    unsigned short* kbfT = (unsigned short*)(ws + 3670016);  // 1,048,576 us [c][j]
    unsigned short* qbf  = (unsigned short*)(ws + 4194304);  // 1,048,576 us [n][j]
    unsigned short* Wvbf = (unsigned short*)(ws + 4718592);  //   262,144 us
    unsigned short* ctxT = (unsigned short*)kT;              // 2,097,152 us; aliases kT (dead after softmax_k)

    unsigned short* xTbf = (unsigned short*)d_out;           // 67.1M us in out region (dead before out_mfma)
    unsigned short* Tbf  = (unsigned short*)(out + OUT_ELEMS); // 16.8M us in attn region (dead before attn_mfma)

    prep<<<dim3(32, 8), 256, 0, stream>>>(x, xbar, xTbf);
    tobf16<<<128, 256, 0, stream>>>(Wv, Wvbf);
    gemm_nt<<<dim3(8, 32), 256, 0, stream>>>(xbar, 512, Wq, 512, qsm, 512, 512, bq, 0);
    gemm_nt<<<dim3(32, 8), 256, 0, stream>>>(Wk, 512, xbar, 512, kT, 2048, 512, bk, 1);
    softmax_q<<<4096, 256, 0, stream>>>(qsm, qbf);
    softmax_k<<<512, 256, 0, stream>>>(kT, kbf, kbfT);
    t_gemm<<<dim3(4, 4, 64), 256, 0, stream>>>(kbf, xTbf, Tbf);
    ctx_mfma<<<128, 256, 0, stream>>>(Tbf, Wvbf, ctxT);
    out_mfma<<<dim3(16, 64), 256, 0, stream>>>(qbf, ctxT, bv, out);
    attn_mfma<<<dim3(16, 16, 8), 256, 0, stream>>>(qbf, kbfT, out + OUT_ELEMS);
}